// Round 1
// baseline (949.024 us; speedup 1.0000x reference)
//
#include <hip/hip_runtime.h>
#include <math.h>

#define HH 1024
#define WW 1024
#define CD 900
#define MS 10
#define CS 62            // (H-CD)/2
#define OFFT 72          // MS+CS
#define TW 880           // H-2*OFF
#define SS 21            // 2*MS+1
#define NT (TW*TW)       // 774400
#define NCC_N (CD*CD)    // 810000
#define EPSV 1e-8

// ws layout:
//   bytes [0..24)    : 3 doubles: sum_t, sum_t2, sum_X   (must be zeroed)
//   bytes [32..32+441*4) : float ncc[441]
//   bytes [1824..1832)   : float xs, ys

__global__ void reduce_sums_kernel(const float* __restrict__ X,
                                   const float* __restrict__ T,
                                   double* __restrict__ sums) {
    double a0 = 0.0, a1 = 0.0, a2 = 0.0;
    int tid = blockIdx.x * blockDim.x + threadIdx.x;
    int stride = gridDim.x * blockDim.x;
    for (int k = tid; k < NT; k += stride) {
        int u = k / TW, v = k - u * TW;
        float t = T[(OFFT + u) * WW + (OFFT + v)];
        a0 += (double)t;
        a1 += (double)t * (double)t;
    }
    for (int k = tid; k < NCC_N; k += stride) {
        int u = k / CD, v = k - u * CD;
        a2 += (double)X[(CS + u) * WW + (CS + v)];
    }
    // wave reduce (64 lanes)
    for (int off = 32; off > 0; off >>= 1) {
        a0 += __shfl_down(a0, off);
        a1 += __shfl_down(a1, off);
        a2 += __shfl_down(a2, off);
    }
    __shared__ double red[3][4];
    int lane = threadIdx.x & 63, wid = threadIdx.x >> 6;
    if (lane == 0) { red[0][wid] = a0; red[1][wid] = a1; red[2][wid] = a2; }
    __syncthreads();
    if (threadIdx.x == 0) {
        double s0 = 0, s1 = 0, s2 = 0;
        for (int w = 0; w < 4; ++w) { s0 += red[0][w]; s1 += red[1][w]; s2 += red[2][w]; }
        atomicAdd(&sums[0], s0);
        atomicAdd(&sums[1], s1);
        atomicAdd(&sums[2], s2);
    }
}

// One block per (i,j) shift: cross-correlation + window sums, fused.
__global__ __launch_bounds__(256) void ncc_kernel(const float* __restrict__ X,
                                                  const float* __restrict__ T,
                                                  const double* __restrict__ sums,
                                                  float* __restrict__ ncc) {
    const int j = blockIdx.x;   // column shift
    const int i = blockIdx.y;   // row shift
    const int tid = threadIdx.x;

    const double meant_d = sums[0] / (double)NT;
    const double meanX_d = sums[2] / (double)NCC_N;
    const float fmt = (float)meant_d;
    const float fmx = (float)meanX_d;

    const float* __restrict__ Xbase = X + (CS + i) * WW + (CS + j);
    const float* __restrict__ Tbase = T + OFFT * WW + OFFT;

    float acc_c = 0.f, acc_s = 0.f, acc_s2 = 0.f;
    for (int u = 0; u < TW; ++u) {
        const float* xr = Xbase + u * WW;
        const float* tr = Tbase + u * WW;
        for (int v = tid; v < TW; v += 256) {
            float x = xr[v];
            float t = tr[v];
            acc_c += (x - fmx) * (t - fmt);
            acc_s += x;
            acc_s2 += x * x;
        }
    }

    double d0 = (double)acc_c, d1 = (double)acc_s, d2 = (double)acc_s2;
    for (int off = 32; off > 0; off >>= 1) {
        d0 += __shfl_down(d0, off);
        d1 += __shfl_down(d1, off);
        d2 += __shfl_down(d2, off);
    }
    __shared__ double red[3][4];
    int lane = tid & 63, wid = tid >> 6;
    if (lane == 0) { red[0][wid] = d0; red[1][wid] = d1; red[2][wid] = d2; }
    __syncthreads();
    if (tid == 0) {
        double cross = 0, sx = 0, sxx = 0;
        for (int w = 0; w < 4; ++w) { cross += red[0][w]; sx += red[1][w]; sxx += red[2][w]; }
        double tvar = sums[1] - sums[0] * sums[0] / (double)NT + EPSV;
        double var = sxx - sx * sx / (double)NT + EPSV;
        if (var < 0.0) var = 0.0;
        double denom = sqrt(tvar * var);
        float val = (float)(cross / denom);
        if (isnan(val)) val = 0.f;
        ncc[i * SS + j] = val;
    }
}

__global__ void argmax_kernel(const float* __restrict__ ncc,
                              float* __restrict__ xy,
                              float* __restrict__ out_tail) {
    __shared__ float sv[512];
    __shared__ int   si[512];
    int tid = threadIdx.x;
    float v = (tid < SS * SS) ? ncc[tid] : -1e30f;
    sv[tid] = v;
    si[tid] = tid;
    __syncthreads();
    for (int off = 256; off > 0; off >>= 1) {
        if (tid < off) {
            float v2 = sv[tid + off];
            int   i2 = si[tid + off];
            if (v2 > sv[tid] || (v2 == sv[tid] && i2 < si[tid])) {
                sv[tid] = v2; si[tid] = i2;
            }
        }
        __syncthreads();
    }
    if (tid == 0) {
        int idx = si[0];
        int sx = idx / SS;
        int sy = idx - sx * SS;
        auto at = [&](int r, int c) -> float {
            r = r < 0 ? 0 : (r > SS - 1 ? SS - 1 : r);
            c = c < 0 ? 0 : (c > SS - 1 ? SS - 1 : c);
            return logf(ncc[r * SS + c]);
        };
        float l4  = 4.0f * at(sx, sy);
        float lxm = at(sx - 1, sy), lxp = at(sx + 1, sy);
        float lym = at(sx, sy - 1), lyp = at(sx, sy + 1);
        float xs = -((float)sx - (float)MS) - (lxm - lxp) / (2.0f * lxm - l4 + 2.0f * lxp);
        float ys = -((float)sy - (float)MS) - (lym - lyp) / (2.0f * lym - l4 + 2.0f * lyp);
        xy[0] = xs; xy[1] = ys;
        out_tail[0] = xs; out_tail[1] = ys;
    }
}

// out[r,c] stored transposed: d_out[c*H + r].  thread.x -> r so writes coalesce.
__global__ __launch_bounds__(256) void shift_kernel(const float* __restrict__ img,
                                                    const float* __restrict__ xy,
                                                    float* __restrict__ out) {
    int r = blockIdx.x * blockDim.x + threadIdx.x;
    int c = blockIdx.y;
    float xs = xy[0], ys = xy[1];
    float rr = (float)r - xs;
    float cc = (float)c - ys;
    float r0f = floorf(rr), c0f = floorf(cc);
    float wr = rr - r0f, wc = cc - c0f;
    int r0 = (int)r0f, c0 = (int)c0f;

    auto samp = [&](int ri, int ci) -> float {
        bool valid = (ri >= 0) & (ri < HH) & (ci >= 0) & (ci < WW);
        int rcl = ri < 0 ? 0 : (ri > HH - 1 ? HH - 1 : ri);
        int ccl = ci < 0 ? 0 : (ci > WW - 1 ? WW - 1 : ci);
        float v = img[rcl * WW + ccl];
        return valid ? v : 0.0f;
    };

    float s00 = samp(r0, c0);
    float s01 = samp(r0, c0 + 1);
    float s10 = samp(r0 + 1, c0);
    float s11 = samp(r0 + 1, c0 + 1);
    float o = (1.f - wr) * (1.f - wc) * s00 + (1.f - wr) * wc * s01 +
              wr * (1.f - wc) * s10 + wr * wc * s11;
    out[c * HH + r] = o;
}

extern "C" void kernel_launch(void* const* d_in, const int* in_sizes, int n_in,
                              void* d_out, int out_size, void* d_ws, size_t ws_size,
                              hipStream_t stream) {
    const float* X = (const float*)d_in[0];
    const float* T = (const float*)d_in[1];
    float* out = (float*)d_out;

    double* sums = (double*)d_ws;
    float* ncc = (float*)((char*)d_ws + 32);
    float* xy  = (float*)((char*)d_ws + 32 + 448 * 4);  // after ncc (padded)

    hipMemsetAsync(d_ws, 0, 32, stream);

    reduce_sums_kernel<<<256, 256, 0, stream>>>(X, T, sums);
    ncc_kernel<<<dim3(SS, SS), 256, 0, stream>>>(X, T, sums, ncc);
    argmax_kernel<<<1, 512, 0, stream>>>(ncc, xy, out + (size_t)HH * WW);
    shift_kernel<<<dim3(HH / 256, WW), 256, 0, stream>>>(X, xy, out);
}

// Round 2
// 140.016 us; speedup vs baseline: 6.7779x; 6.7779x over previous
//
#include <hip/hip_runtime.h>
#include <math.h>

#define HH 1024
#define WW 1024
#define CD 900
#define MS 10
#define CS 62            // (H-CD)/2
#define OFFT 72          // MS+CS
#define TW 880           // H-2*OFF
#define SS 21            // 2*MS+1
#define EPSV 1e-8
#define NBAND 55         // 880/16 bands of template rows
#define RPB 16           // template rows per corr block

// ---------------- row statistics ----------------
// blocks [0,900): X crop rows -> sliding window sums RS1/RS2 (21 lags) + full row sum
// blocks [900,1780): template rows -> row sum / sumsq
__global__ __launch_bounds__(256) void row_stats_kernel(const float* __restrict__ X,
                                                        const float* __restrict__ T,
                                                        float* __restrict__ RS1,
                                                        float* __restrict__ RS2,
                                                        float* __restrict__ Sfull,
                                                        float* __restrict__ Trow1,
                                                        float* __restrict__ Trow2) {
    const int b = blockIdx.x, tid = threadIdx.x;
    __shared__ float red[4][3];
    const int lane = tid & 63, wid = tid >> 6;
    if (b < CD) {
        const float* row = X + (CS + b) * WW + CS;   // 900 valid cols
        float sf = 0.f, sw = 0.f, qw = 0.f;
        for (int v = tid; v < CD; v += 256) {
            float x = row[v];
            sf += x;
            if (v < TW) { sw += x; qw += x * x; }
        }
        for (int m = 1; m < 64; m <<= 1) {
            sf += __shfl_xor(sf, m); sw += __shfl_xor(sw, m); qw += __shfl_xor(qw, m);
        }
        if (lane == 0) { red[wid][0] = sf; red[wid][1] = sw; red[wid][2] = qw; }
        __syncthreads();
        if (tid == 0) {
            sf = red[0][0] + red[1][0] + red[2][0] + red[3][0];
            sw = red[0][1] + red[1][1] + red[2][1] + red[3][1];
            qw = red[0][2] + red[1][2] + red[2][2] + red[3][2];
            Sfull[b] = sf;
            float w1 = sw, w2 = qw;
            RS1[b * SS] = w1; RS2[b * SS] = w2;
            for (int j = 0; j < SS - 1; ++j) {     // incremental window slide
                float a = row[j], c = row[TW + j];
                w1 += c - a;
                w2 += c * c - a * a;
                RS1[b * SS + j + 1] = w1;
                RS2[b * SS + j + 1] = w2;
            }
        }
    } else {
        const int u = b - CD;
        const float* row = T + (OFFT + u) * WW + OFFT;
        float s = 0.f, q = 0.f;
        for (int v = tid; v < TW; v += 256) { float t = row[v]; s += t; q += t * t; }
        for (int m = 1; m < 64; m <<= 1) { s += __shfl_xor(s, m); q += __shfl_xor(q, m); }
        if (lane == 0) { red[wid][0] = s; red[wid][1] = q; }
        __syncthreads();
        if (tid == 0) {
            Trow1[u] = red[0][0] + red[1][0] + red[2][0] + red[3][0];
            Trow2[u] = red[0][1] + red[1][1] + red[2][1] + red[3][1];
        }
    }
}

__global__ void stats_final_kernel(const float* __restrict__ Trow1,
                                   const float* __restrict__ Trow2,
                                   const float* __restrict__ Sfull,
                                   double* __restrict__ dsums) {
    const int tid = threadIdx.x;
    double a = 0, b = 0, c = 0;
    for (int k = tid; k < TW; k += 256) { a += (double)Trow1[k]; b += (double)Trow2[k]; }
    for (int k = tid; k < CD; k += 256) c += (double)Sfull[k];
    for (int m = 1; m < 64; m <<= 1) {
        a += __shfl_xor(a, m); b += __shfl_xor(b, m); c += __shfl_xor(c, m);
    }
    __shared__ double red[4][3];
    const int lane = tid & 63, wid = tid >> 6;
    if (lane == 0) { red[wid][0] = a; red[wid][1] = b; red[wid][2] = c; }
    __syncthreads();
    if (tid == 0) {
        dsums[0] = red[0][0] + red[1][0] + red[2][0] + red[3][0];
        dsums[1] = red[0][1] + red[1][1] + red[2][1] + red[3][1];
        dsums[2] = red[0][2] + red[1][2] + red[2][2] + red[3][2];
    }
}

// ---------------- raw cross-correlation ----------------
// block (band, i): 16 template rows u0..u0+15 vs X rows CS+i+u, all 21 column lags.
// 256 threads = 2 rows x 128 v-threads; active v-threads: 110 x chunk-8 = 880.
__global__ __launch_bounds__(256) void corr_kernel(const float* __restrict__ X,
                                                   const float* __restrict__ T,
                                                   float* __restrict__ part) {
    __shared__ __align__(16) float Xs[2][904];   // 900 used
    __shared__ __align__(16) float Ts[2][880];
    __shared__ float red[4][SS];

    const int band = blockIdx.x, i = blockIdx.y;
    const int tid = threadIdx.x;
    const int u0 = band * RPB;
    const int tr = tid >> 7, tv = tid & 127;
    const int v0 = tv * 8;

    float acc[SS];
#pragma unroll
    for (int j = 0; j < SS; ++j) acc[j] = 0.f;

    for (int p = 0; p < RPB / 2; ++p) {
        const int u = u0 + 2 * p;
        const float* x0 = X + (CS + i + u) * WW + CS;
        const float* x1 = x0 + WW;
        const float* t0 = T + (OFFT + u) * WW + OFFT;
        const float* t1 = t0 + WW;
        for (int v = tid; v < CD; v += 256) { Xs[0][v] = x0[v]; Xs[1][v] = x1[v]; }
        for (int v = tid; v < TW; v += 256) { Ts[0][v] = t0[v]; Ts[1][v] = t1[v]; }
        __syncthreads();
        if (tv < 110) {
            float x[28], t[8];
            const float4* xp = (const float4*)(&Xs[tr][v0]);
            const float4* tp = (const float4*)(&Ts[tr][v0]);
#pragma unroll
            for (int k = 0; k < 7; ++k) {
                float4 q = xp[k];
                x[4 * k] = q.x; x[4 * k + 1] = q.y; x[4 * k + 2] = q.z; x[4 * k + 3] = q.w;
            }
#pragma unroll
            for (int k = 0; k < 2; ++k) {
                float4 q = tp[k];
                t[4 * k] = q.x; t[4 * k + 1] = q.y; t[4 * k + 2] = q.z; t[4 * k + 3] = q.w;
            }
#pragma unroll
            for (int j = 0; j < SS; ++j) {
                float a = acc[j];
#pragma unroll
                for (int k = 0; k < 8; ++k) a = fmaf(x[j + k], t[k], a);
                acc[j] = a;
            }
        }
        __syncthreads();
    }

#pragma unroll
    for (int j = 0; j < SS; ++j)
#pragma unroll
        for (int m = 1; m < 64; m <<= 1) acc[j] += __shfl_xor(acc[j], m);

    const int lane = tid & 63, wid = tid >> 6;
    if (lane == 0) {
#pragma unroll
        for (int j = 0; j < SS; ++j) red[wid][j] = acc[j];
    }
    __syncthreads();
    if (tid < SS) {
        float s = red[0][tid] + red[1][tid] + red[2][tid] + red[3][tid];
        part[(i * NBAND + band) * SS + tid] = s;
    }
}

// ---------------- combine -> ncc ----------------
__global__ __launch_bounds__(128) void ncc_final_kernel(const float* __restrict__ part,
                                                        const float* __restrict__ RS1,
                                                        const float* __restrict__ RS2,
                                                        const double* __restrict__ dsums,
                                                        float* __restrict__ ncc) {
    const int bid = blockIdx.x;
    const int i = bid / SS, j = bid - i * SS;
    const int tid = threadIdx.x;
    float d = 0.f, s1 = 0.f, s2 = 0.f;
    for (int b = tid; b < NBAND; b += 128) d += part[(i * NBAND + b) * SS + j];
    for (int u = tid; u < TW; u += 128) {
        s1 += RS1[(i + u) * SS + j];
        s2 += RS2[(i + u) * SS + j];
    }
    double dd = d, d1 = s1, d2 = s2;
    for (int m = 1; m < 64; m <<= 1) {
        dd += __shfl_xor(dd, m); d1 += __shfl_xor(d1, m); d2 += __shfl_xor(d2, m);
    }
    __shared__ double red[2][3];
    const int lane = tid & 63, wid = tid >> 6;
    if (lane == 0) { red[wid][0] = dd; red[wid][1] = d1; red[wid][2] = d2; }
    __syncthreads();
    if (tid == 0) {
        double dot = red[0][0] + red[1][0];
        double S1 = red[0][1] + red[1][1];
        double S2 = red[0][2] + red[1][2];
        double sum_t = dsums[0], sum_t2 = dsums[1], sumX = dsums[2];
        const double NT = 774400.0;
        double mt = sum_t / NT, mx = sumX / 810000.0;
        double tvar = sum_t2 - sum_t * sum_t / NT + EPSV;
        double var = S2 - S1 * S1 / NT + EPSV;
        if (var < 0.0) var = 0.0;
        double cross = dot - mt * S1 - mx * sum_t + NT * mx * mt;
        float val = (float)(cross / sqrt(tvar * var));
        if (isnan(val)) val = 0.f;
        ncc[i * SS + j] = val;
    }
}

// ---------------- argmax + subpixel ----------------
__global__ void argmax_kernel(const float* __restrict__ ncc,
                              float* __restrict__ xy,
                              float* __restrict__ out_tail) {
    __shared__ float sv[512];
    __shared__ int si[512];
    int tid = threadIdx.x;
    float v = (tid < SS * SS) ? ncc[tid] : -1e30f;
    sv[tid] = v;
    si[tid] = tid;
    __syncthreads();
    for (int off = 256; off > 0; off >>= 1) {
        if (tid < off) {
            float v2 = sv[tid + off];
            int i2 = si[tid + off];
            if (v2 > sv[tid] || (v2 == sv[tid] && i2 < si[tid])) { sv[tid] = v2; si[tid] = i2; }
        }
        __syncthreads();
    }
    if (tid == 0) {
        int idx = si[0];
        int sx = idx / SS;
        int sy = idx - sx * SS;
        auto at = [&](int r, int c) -> float {
            r = r < 0 ? 0 : (r > SS - 1 ? SS - 1 : r);
            c = c < 0 ? 0 : (c > SS - 1 ? SS - 1 : c);
            return logf(ncc[r * SS + c]);
        };
        float l4 = 4.0f * at(sx, sy);
        float lxm = at(sx - 1, sy), lxp = at(sx + 1, sy);
        float lym = at(sx, sy - 1), lyp = at(sx, sy + 1);
        float xs = -((float)sx - (float)MS) - (lxm - lxp) / (2.0f * lxm - l4 + 2.0f * lxp);
        float ys = -((float)sy - (float)MS) - (lym - lyp) / (2.0f * lym - l4 + 2.0f * lyp);
        xy[0] = xs; xy[1] = ys;
        out_tail[0] = xs; out_tail[1] = ys;
    }
}

// ---------------- bilinear shift (transposed store) ----------------
__global__ __launch_bounds__(256) void shift_kernel(const float* __restrict__ img,
                                                    const float* __restrict__ xy,
                                                    float* __restrict__ out) {
    int r = blockIdx.x * blockDim.x + threadIdx.x;
    int c = blockIdx.y;
    float xs = xy[0], ys = xy[1];
    float rr = (float)r - xs;
    float cc = (float)c - ys;
    float r0f = floorf(rr), c0f = floorf(cc);
    float wr = rr - r0f, wc = cc - c0f;
    int r0 = (int)r0f, c0 = (int)c0f;

    auto samp = [&](int ri, int ci) -> float {
        bool valid = (ri >= 0) & (ri < HH) & (ci >= 0) & (ci < WW);
        int rcl = ri < 0 ? 0 : (ri > HH - 1 ? HH - 1 : ri);
        int ccl = ci < 0 ? 0 : (ci > WW - 1 ? WW - 1 : ci);
        float v = img[rcl * WW + ccl];
        return valid ? v : 0.0f;
    };

    float s00 = samp(r0, c0);
    float s01 = samp(r0, c0 + 1);
    float s10 = samp(r0 + 1, c0);
    float s11 = samp(r0 + 1, c0 + 1);
    float o = (1.f - wr) * (1.f - wc) * s00 + (1.f - wr) * wc * s01 +
              wr * (1.f - wc) * s10 + wr * wc * s11;
    out[c * HH + r] = o;
}

extern "C" void kernel_launch(void* const* d_in, const int* in_sizes, int n_in,
                              void* d_out, int out_size, void* d_ws, size_t ws_size,
                              hipStream_t stream) {
    const float* X = (const float*)d_in[0];
    const float* T = (const float*)d_in[1];
    float* out = (float*)d_out;

    char* w = (char*)d_ws;
    double* dsums = (double*)w;                       // 32 B
    float* ncc = (float*)(w + 32);                    // 441 f
    float* xy = (float*)(w + 1824);                   // 2 f
    float* Trow1 = (float*)(w + 1840);                // 880 f
    float* Trow2 = (float*)(w + 1840 + 3520);         // 880 f
    float* Sfull = (float*)(w + 1840 + 7040);         // 900 f
    float* RS1 = (float*)(w + 1840 + 10640);          // 900*21 f
    float* RS2 = (float*)(w + 1840 + 86240);          // 900*21 f
    float* part = (float*)(w + 1840 + 161840);        // 21*55*21 f

    row_stats_kernel<<<CD + TW, 256, 0, stream>>>(X, T, RS1, RS2, Sfull, Trow1, Trow2);
    stats_final_kernel<<<1, 256, 0, stream>>>(Trow1, Trow2, Sfull, dsums);
    corr_kernel<<<dim3(NBAND, SS), 256, 0, stream>>>(X, T, part);
    ncc_final_kernel<<<SS * SS, 128, 0, stream>>>(part, RS1, RS2, dsums, ncc);
    argmax_kernel<<<1, 512, 0, stream>>>(ncc, xy, out + (size_t)HH * WW);
    shift_kernel<<<dim3(HH / 256, WW), 256, 0, stream>>>(X, xy, out);
}

// Round 3
// 128.763 us; speedup vs baseline: 7.3703x; 1.0874x over previous
//
#include <hip/hip_runtime.h>
#include <math.h>

#define HH 1024
#define WW 1024
#define CD 900
#define MS 10
#define CS 62            // (H-CD)/2
#define OFFT 72          // MS+CS
#define TW 880           // H-2*OFF
#define SS 21            // 2*MS+1
#define EPSV 1e-8
#define NBAND 55         // 880/16 bands of template rows
#define RPB 16           // template rows per corr block
#define NCHUNK 110       // 880/8 column chunks

// ws layout:
//   0      : 3 doubles (sum_t, sum_t2, sumX) -- zeroed by memset
//   32     : float ncc[441]
//   1800   : float xy[2]
//   1824   : float RS1T[21*900]   (transposed: [j][row])
//   77424  : float RS2T[21*900]
//   153024 : float part[21*55*21]

// ---------------- row statistics (+ global sums via f64 atomics) ----------------
__global__ __launch_bounds__(256) void row_stats_kernel(const float* __restrict__ X,
                                                        const float* __restrict__ T,
                                                        float* __restrict__ RS1T,
                                                        float* __restrict__ RS2T,
                                                        double* __restrict__ dsums) {
    const int b = blockIdx.x, tid = threadIdx.x;
    __shared__ float red[4][3];
    const int lane = tid & 63, wid = tid >> 6;
    if (b < CD) {
        const float* row = X + (size_t)(CS + b) * WW + CS;   // 900 valid cols
        float sf = 0.f, sw = 0.f, qw = 0.f;
        for (int v = tid; v < CD; v += 256) {
            float x = row[v];
            sf += x;
            if (v < TW) { sw += x; qw += x * x; }
        }
        for (int m = 1; m < 64; m <<= 1) {
            sf += __shfl_xor(sf, m); sw += __shfl_xor(sw, m); qw += __shfl_xor(qw, m);
        }
        if (lane == 0) { red[wid][0] = sf; red[wid][1] = sw; red[wid][2] = qw; }
        __syncthreads();
        if (tid == 0) {
            sf = red[0][0] + red[1][0] + red[2][0] + red[3][0];
            sw = red[0][1] + red[1][1] + red[2][1] + red[3][1];
            qw = red[0][2] + red[1][2] + red[2][2] + red[3][2];
            atomicAdd(&dsums[2], (double)sf);
            float w1 = sw, w2 = qw;
            RS1T[b] = w1; RS2T[b] = w2;                 // j = 0
            for (int j = 0; j < SS - 1; ++j) {          // incremental slide
                float a = row[j], c = row[TW + j];
                w1 += c - a;
                w2 += c * c - a * a;
                RS1T[(j + 1) * CD + b] = w1;
                RS2T[(j + 1) * CD + b] = w2;
            }
        }
    } else {
        const int u = b - CD;
        const float* row = T + (size_t)(OFFT + u) * WW + OFFT;
        float s = 0.f, q = 0.f;
        for (int v = tid; v < TW; v += 256) { float t = row[v]; s += t; q += t * t; }
        for (int m = 1; m < 64; m <<= 1) { s += __shfl_xor(s, m); q += __shfl_xor(q, m); }
        if (lane == 0) { red[wid][0] = s; red[wid][1] = q; }
        __syncthreads();
        if (tid == 0) {
            atomicAdd(&dsums[0], (double)(red[0][0] + red[1][0] + red[2][0] + red[3][0]));
            atomicAdd(&dsums[1], (double)(red[0][1] + red[1][1] + red[2][1] + red[3][1]));
        }
    }
}

// ---------------- raw cross-correlation: registers only, no LDS staging ----------------
// block (band, i): 16 template rows vs X rows CS+i+u, all 21 column lags.
// item = (row-in-band, 8-col chunk); each thread: 8 aligned float4 x-loads + 2 t-loads,
// 168 FMAs. No inter-thread X reuse exists, so LDS would only add conflicts.
__global__ __launch_bounds__(256) void corr_kernel(const float* __restrict__ X,
                                                   const float* __restrict__ T,
                                                   float* __restrict__ part) {
    const int band = blockIdx.x, i = blockIdx.y;
    const int tid = threadIdx.x;
    const int u0 = band * RPB;

    float acc[SS];
#pragma unroll
    for (int j = 0; j < SS; ++j) acc[j] = 0.f;

    for (int item = tid; item < RPB * NCHUNK; item += 256) {
        const int ul = item / NCHUNK;
        const int c = item - ul * NCHUNK;
        const int u = u0 + ul;
        // x: cols [60+8c, 92+8c): 16B-aligned (60+8c ≡ 0 mod 4); needed = cols 62+8c+j+k
        const float4* xp = (const float4*)(X + (size_t)(CS + i + u) * WW + 60 + c * 8);
        // t: cols [72+8c, 80+8c): aligned
        const float4* tp = (const float4*)(T + (size_t)(OFFT + u) * WW + OFFT + c * 8);
        float xr[32], t[8];
#pragma unroll
        for (int k = 0; k < 8; ++k) {
            float4 q = xp[k];
            xr[4 * k] = q.x; xr[4 * k + 1] = q.y; xr[4 * k + 2] = q.z; xr[4 * k + 3] = q.w;
        }
        {
            float4 q0 = tp[0], q1 = tp[1];
            t[0] = q0.x; t[1] = q0.y; t[2] = q0.z; t[3] = q0.w;
            t[4] = q1.x; t[5] = q1.y; t[6] = q1.z; t[7] = q1.w;
        }
#pragma unroll
        for (int j = 0; j < SS; ++j) {
            float a = acc[j];
#pragma unroll
            for (int k = 0; k < 8; ++k) a = fmaf(xr[2 + j + k], t[k], a);
            acc[j] = a;
        }
    }

#pragma unroll
    for (int j = 0; j < SS; ++j)
#pragma unroll
        for (int m = 1; m < 64; m <<= 1) acc[j] += __shfl_xor(acc[j], m);

    __shared__ float red[4][SS];
    const int lane = tid & 63, wid = tid >> 6;
    if (lane == 0) {
#pragma unroll
        for (int j = 0; j < SS; ++j) red[wid][j] = acc[j];
    }
    __syncthreads();
    if (tid < SS) {
        float s = red[0][tid] + red[1][tid] + red[2][tid] + red[3][tid];
        part[(i * NBAND + band) * SS + tid] = s;
    }
}

// ---------------- combine -> ncc ----------------
__global__ __launch_bounds__(256) void ncc_final_kernel(const float* __restrict__ part,
                                                        const float* __restrict__ RS1T,
                                                        const float* __restrict__ RS2T,
                                                        const double* __restrict__ dsums,
                                                        float* __restrict__ ncc) {
    const int bid = blockIdx.x;
    const int i = bid / SS, j = bid - i * SS;
    const int tid = threadIdx.x;
    float d = 0.f, s1 = 0.f, s2 = 0.f;
    for (int b = tid; b < NBAND; b += 256) d += part[(i * NBAND + b) * SS + j];
    const float* r1 = RS1T + j * CD + i;   // contiguous 880 floats
    const float* r2 = RS2T + j * CD + i;
    for (int u = tid; u < TW; u += 256) { s1 += r1[u]; s2 += r2[u]; }
    double dd = d, d1 = s1, d2 = s2;
    for (int m = 1; m < 64; m <<= 1) {
        dd += __shfl_xor(dd, m); d1 += __shfl_xor(d1, m); d2 += __shfl_xor(d2, m);
    }
    __shared__ double red[4][3];
    const int lane = tid & 63, wid = tid >> 6;
    if (lane == 0) { red[wid][0] = dd; red[wid][1] = d1; red[wid][2] = d2; }
    __syncthreads();
    if (tid == 0) {
        double dot = red[0][0] + red[1][0] + red[2][0] + red[3][0];
        double S1 = red[0][1] + red[1][1] + red[2][1] + red[3][1];
        double S2 = red[0][2] + red[1][2] + red[2][2] + red[3][2];
        double sum_t = dsums[0], sum_t2 = dsums[1], sumX = dsums[2];
        const double NT = 774400.0;
        double mt = sum_t / NT, mx = sumX / 810000.0;
        double tvar = sum_t2 - sum_t * sum_t / NT + EPSV;
        double var = S2 - S1 * S1 / NT + EPSV;
        if (var < 0.0) var = 0.0;
        double cross = dot - mt * S1 - mx * sum_t + NT * mx * mt;
        float val = (float)(cross / sqrt(tvar * var));
        if (isnan(val)) val = 0.f;
        ncc[i * SS + j] = val;
    }
}

// ---------------- argmax + subpixel ----------------
__global__ void argmax_kernel(const float* __restrict__ ncc,
                              float* __restrict__ xy,
                              float* __restrict__ out_tail) {
    __shared__ float sv[512];
    __shared__ int si[512];
    int tid = threadIdx.x;
    float v = (tid < SS * SS) ? ncc[tid] : -1e30f;
    sv[tid] = v;
    si[tid] = tid;
    __syncthreads();
    for (int off = 256; off > 0; off >>= 1) {
        if (tid < off) {
            float v2 = sv[tid + off];
            int i2 = si[tid + off];
            if (v2 > sv[tid] || (v2 == sv[tid] && i2 < si[tid])) { sv[tid] = v2; si[tid] = i2; }
        }
        __syncthreads();
    }
    if (tid == 0) {
        int idx = si[0];
        int sx = idx / SS;
        int sy = idx - sx * SS;
        auto at = [&](int r, int c) -> float {
            r = r < 0 ? 0 : (r > SS - 1 ? SS - 1 : r);
            c = c < 0 ? 0 : (c > SS - 1 ? SS - 1 : c);
            return logf(ncc[r * SS + c]);
        };
        float l4 = 4.0f * at(sx, sy);
        float lxm = at(sx - 1, sy), lxp = at(sx + 1, sy);
        float lym = at(sx, sy - 1), lyp = at(sx, sy + 1);
        float xs = -((float)sx - (float)MS) - (lxm - lxp) / (2.0f * lxm - l4 + 2.0f * lxp);
        float ys = -((float)sy - (float)MS) - (lym - lyp) / (2.0f * lym - l4 + 2.0f * lyp);
        xy[0] = xs; xy[1] = ys;
        out_tail[0] = xs; out_tail[1] = ys;
    }
}

// ---------------- bilinear shift, 64x64 LDS transpose tile ----------------
// Phase 1: lane->c (coalesced img reads), store tile[r][c].
// Phase 2: lane->r (coalesced transposed writes), read tile[r][c] stride-65 (conflict-free).
__global__ __launch_bounds__(256) void shift_kernel(const float* __restrict__ img,
                                                    const float* __restrict__ xy,
                                                    float* __restrict__ out) {
    __shared__ float tile[64][65];
    const int R0 = blockIdx.y * 64, C0 = blockIdx.x * 64;
    const float xs = xy[0], ys = xy[1];
    const int tid = threadIdx.x;

    {
        const int cl = tid & 63, rg = tid >> 6;
        const int c = C0 + cl;
        const float cc = (float)c - ys;
        const float c0f = floorf(cc);
        const float wc = cc - c0f;
        const int c0 = (int)c0f;
        const bool vc0 = (c0 >= 0) & (c0 < WW);
        const bool vc1 = (c0 + 1 >= 0) & (c0 + 1 < WW);
        const int c0c = c0 < 0 ? 0 : (c0 > WW - 1 ? WW - 1 : c0);
        const int c1c = (c0 + 1) < 0 ? 0 : ((c0 + 1) > WW - 1 ? WW - 1 : c0 + 1);
        for (int k = 0; k < 16; ++k) {
            const int rl = rg * 16 + k;
            const int r = R0 + rl;
            const float rr = (float)r - xs;
            const float r0f = floorf(rr);
            const float wr = rr - r0f;
            const int r0 = (int)r0f;
            const bool vr0 = (r0 >= 0) & (r0 < HH);
            const bool vr1 = (r0 + 1 >= 0) & (r0 + 1 < HH);
            const int r0c = r0 < 0 ? 0 : (r0 > HH - 1 ? HH - 1 : r0);
            const int r1c = (r0 + 1) < 0 ? 0 : ((r0 + 1) > HH - 1 ? HH - 1 : r0 + 1);
            float s00 = img[(size_t)r0c * WW + c0c]; if (!(vr0 & vc0)) s00 = 0.f;
            float s01 = img[(size_t)r0c * WW + c1c]; if (!(vr0 & vc1)) s01 = 0.f;
            float s10 = img[(size_t)r1c * WW + c0c]; if (!(vr1 & vc0)) s10 = 0.f;
            float s11 = img[(size_t)r1c * WW + c1c]; if (!(vr1 & vc1)) s11 = 0.f;
            tile[rl][cl] = (1.f - wr) * (1.f - wc) * s00 + (1.f - wr) * wc * s01 +
                           wr * (1.f - wc) * s10 + wr * wc * s11;
        }
    }
    __syncthreads();
    {
        const int rl = tid & 63, cg = tid >> 6;
        for (int k = 0; k < 16; ++k) {
            const int cl = cg * 16 + k;
            out[(size_t)(C0 + cl) * HH + R0 + rl] = tile[rl][cl];
        }
    }
}

extern "C" void kernel_launch(void* const* d_in, const int* in_sizes, int n_in,
                              void* d_out, int out_size, void* d_ws, size_t ws_size,
                              hipStream_t stream) {
    const float* X = (const float*)d_in[0];
    const float* T = (const float*)d_in[1];
    float* out = (float*)d_out;

    char* w = (char*)d_ws;
    double* dsums = (double*)w;
    float* ncc = (float*)(w + 32);
    float* xy = (float*)(w + 1800);
    float* RS1T = (float*)(w + 1824);
    float* RS2T = (float*)(w + 77424);
    float* part = (float*)(w + 153024);

    hipMemsetAsync(dsums, 0, 32, stream);
    row_stats_kernel<<<CD + TW, 256, 0, stream>>>(X, T, RS1T, RS2T, dsums);
    corr_kernel<<<dim3(NBAND, SS), 256, 0, stream>>>(X, T, part);
    ncc_final_kernel<<<SS * SS, 256, 0, stream>>>(part, RS1T, RS2T, dsums, ncc);
    argmax_kernel<<<1, 512, 0, stream>>>(ncc, xy, out + (size_t)HH * WW);
    shift_kernel<<<dim3(16, 16), 256, 0, stream>>>(X, xy, out);
}

// Round 4
// 100.908 us; speedup vs baseline: 9.4048x; 1.2760x over previous
//
#include <hip/hip_runtime.h>
#include <math.h>

#define HH 1024
#define WW 1024
#define CD 900
#define MS 10
#define CS 62            // (H-CD)/2
#define OFFT 72          // MS+CS
#define TW 880           // H-2*OFF
#define SS 21            // 2*MS+1
#define EPSV 1e-8
#define NBAND 55         // 880/16 bands of template rows
#define RPB 16           // template rows per corr block
#define NCH 55           // 880/16 column chunks of 16

// ws layout (floats):
//   RS1T  : w + 0        [21*900]  window sums, transposed [j][row]
//   RS2T  : w + 75600    [21*900]
//   Trow1 : w + 151200   [880]
//   Trow2 : w + 154720   [880]
//   Sfull : w + 158240   [900]
//   part  : w + 161840   [21*55*21]
//   ncc   : w + 258880   [441]

// ---------------- row statistics (no atomics, no memset needed) ----------------
__global__ __launch_bounds__(256) void row_stats_kernel(const float* __restrict__ X,
                                                        const float* __restrict__ T,
                                                        float* __restrict__ RS1T,
                                                        float* __restrict__ RS2T,
                                                        float* __restrict__ Trow1,
                                                        float* __restrict__ Trow2,
                                                        float* __restrict__ Sfull) {
    const int b = blockIdx.x, tid = threadIdx.x;
    __shared__ float red[4][3];
    const int lane = tid & 63, wid = tid >> 6;
    if (b < CD) {
        const float* row = X + (size_t)(CS + b) * WW + CS;   // 900 valid cols
        float sf = 0.f, sw = 0.f, qw = 0.f;
        for (int v = tid; v < CD; v += 256) {
            float x = row[v];
            sf += x;
            if (v < TW) { sw += x; qw += x * x; }
        }
        for (int m = 1; m < 64; m <<= 1) {
            sf += __shfl_xor(sf, m); sw += __shfl_xor(sw, m); qw += __shfl_xor(qw, m);
        }
        if (lane == 0) { red[wid][0] = sf; red[wid][1] = sw; red[wid][2] = qw; }
        __syncthreads();
        if (tid < 32) {
            const float swb = red[0][1] + red[1][1] + red[2][1] + red[3][1];
            const float qwb = red[0][2] + red[1][2] + red[2][2] + red[3][2];
            // lag-j window sum = base + prefix sum of slide deltas (parallel scan)
            float d1 = 0.f, d2 = 0.f;
            if (tid >= 1 && tid < SS) {
                float a = row[tid - 1], c2 = row[TW + tid - 1];
                d1 = c2 - a;
                d2 = c2 * c2 - a * a;
            }
            for (int off = 1; off < 32; off <<= 1) {
                float u1 = __shfl_up(d1, off), u2 = __shfl_up(d2, off);
                if (tid >= off) { d1 += u1; d2 += u2; }
            }
            if (tid < SS) {
                RS1T[tid * CD + b] = swb + d1;
                RS2T[tid * CD + b] = qwb + d2;
            }
            if (tid == 0) Sfull[b] = red[0][0] + red[1][0] + red[2][0] + red[3][0];
        }
    } else {
        const int u = b - CD;
        const float* row = T + (size_t)(OFFT + u) * WW + OFFT;
        float s = 0.f, q = 0.f;
        for (int v = tid; v < TW; v += 256) { float t = row[v]; s += t; q += t * t; }
        for (int m = 1; m < 64; m <<= 1) { s += __shfl_xor(s, m); q += __shfl_xor(q, m); }
        if (lane == 0) { red[wid][0] = s; red[wid][1] = q; }
        __syncthreads();
        if (tid == 0) {
            Trow1[u] = red[0][0] + red[1][0] + red[2][0] + red[3][0];
            Trow2[u] = red[0][1] + red[1][1] + red[2][1] + red[3][1];
        }
    }
}

// ---------------- raw cross-correlation, 16-col chunks, registers only ----------------
// block (band, i): 16 template rows vs X rows CS+i+u, 21 lags.
// item = (row, 16-col chunk): 10+4 float4 loads (224 B) -> 336 FMA (1.5 FMA/B).
__global__ __launch_bounds__(256) void corr_kernel(const float* __restrict__ X,
                                                   const float* __restrict__ T,
                                                   float* __restrict__ part) {
    const int band = blockIdx.x, i = blockIdx.y;
    const int tid = threadIdx.x;
    const int u0 = band * RPB;

    float acc[SS];
#pragma unroll
    for (int j = 0; j < SS; ++j) acc[j] = 0.f;

#pragma unroll 1
    for (int item = tid; item < RPB * NCH; item += 256) {
        const int ul = item / NCH;
        const int c = item - ul * NCH;
        const int u = u0 + ul;
        // x cols [60+16c, 100+16c): 16B-aligned; needed cols 62+16c+j+k (j+k<=35)
        const float4* xp = (const float4*)(X + (size_t)(CS + i + u) * WW + 60 + c * 16);
        // t cols [72+16c, 88+16c): 16B-aligned
        const float4* tp = (const float4*)(T + (size_t)(OFFT + u) * WW + OFFT + c * 16);
        float xr[40], t[16];
#pragma unroll
        for (int k = 0; k < 10; ++k) {
            float4 q = xp[k];
            xr[4 * k] = q.x; xr[4 * k + 1] = q.y; xr[4 * k + 2] = q.z; xr[4 * k + 3] = q.w;
        }
#pragma unroll
        for (int k = 0; k < 4; ++k) {
            float4 q = tp[k];
            t[4 * k] = q.x; t[4 * k + 1] = q.y; t[4 * k + 2] = q.z; t[4 * k + 3] = q.w;
        }
#pragma unroll
        for (int j = 0; j < SS; ++j) {
            float a = acc[j];
#pragma unroll
            for (int k = 0; k < 16; ++k) a = fmaf(xr[2 + j + k], t[k], a);
            acc[j] = a;
        }
    }

#pragma unroll
    for (int j = 0; j < SS; ++j)
#pragma unroll
        for (int m = 1; m < 64; m <<= 1) acc[j] += __shfl_xor(acc[j], m);

    __shared__ float red[4][SS];
    const int lane = tid & 63, wid = tid >> 6;
    if (lane == 0) {
#pragma unroll
        for (int j = 0; j < SS; ++j) red[wid][j] = acc[j];
    }
    __syncthreads();
    if (tid < SS) {
        float s = red[0][tid] + red[1][tid] + red[2][tid] + red[3][tid];
        part[(i * NBAND + band) * SS + tid] = s;
    }
}

// ---------------- combine -> ncc (computes global sums redundantly per block) -----
__global__ __launch_bounds__(256) void ncc_final_kernel(const float* __restrict__ part,
                                                        const float* __restrict__ RS1T,
                                                        const float* __restrict__ RS2T,
                                                        const float* __restrict__ Trow1,
                                                        const float* __restrict__ Trow2,
                                                        const float* __restrict__ Sfull,
                                                        float* __restrict__ ncc) {
    const int bid = blockIdx.x;
    const int i = bid / SS, j = bid - i * SS;
    const int tid = threadIdx.x;
    double dd = 0, d1 = 0, d2 = 0, ta = 0, tb = 0, xs = 0;
    for (int b = tid; b < NBAND; b += 256) dd += (double)part[(i * NBAND + b) * SS + j];
    const float* r1 = RS1T + j * CD + i;   // contiguous
    const float* r2 = RS2T + j * CD + i;
    for (int u = tid; u < TW; u += 256) {
        d1 += (double)r1[u]; d2 += (double)r2[u];
        ta += (double)Trow1[u]; tb += (double)Trow2[u];
    }
    for (int k = tid; k < CD; k += 256) xs += (double)Sfull[k];
    for (int m = 1; m < 64; m <<= 1) {
        dd += __shfl_xor(dd, m); d1 += __shfl_xor(d1, m); d2 += __shfl_xor(d2, m);
        ta += __shfl_xor(ta, m); tb += __shfl_xor(tb, m); xs += __shfl_xor(xs, m);
    }
    __shared__ double red[4][6];
    const int lane = tid & 63, wid = tid >> 6;
    if (lane == 0) {
        red[wid][0] = dd; red[wid][1] = d1; red[wid][2] = d2;
        red[wid][3] = ta; red[wid][4] = tb; red[wid][5] = xs;
    }
    __syncthreads();
    if (tid == 0) {
        double dot = red[0][0] + red[1][0] + red[2][0] + red[3][0];
        double S1  = red[0][1] + red[1][1] + red[2][1] + red[3][1];
        double S2  = red[0][2] + red[1][2] + red[2][2] + red[3][2];
        double sum_t  = red[0][3] + red[1][3] + red[2][3] + red[3][3];
        double sum_t2 = red[0][4] + red[1][4] + red[2][4] + red[3][4];
        double sumX   = red[0][5] + red[1][5] + red[2][5] + red[3][5];
        const double NT = 774400.0;
        double mt = sum_t / NT, mx = sumX / 810000.0;
        double tvar = sum_t2 - sum_t * sum_t / NT + EPSV;
        double var = S2 - S1 * S1 / NT + EPSV;
        if (var < 0.0) var = 0.0;
        double cross = dot - mt * S1 - mx * sum_t + NT * mx * mt;
        float val = (float)(cross / sqrt(tvar * var));
        if (isnan(val)) val = 0.f;
        ncc[i * SS + j] = val;
    }
}

// ---------------- shift with fused argmax+subpixel (redundant per block) ----------
__global__ __launch_bounds__(256) void shift_kernel(const float* __restrict__ img,
                                                    const float* __restrict__ ncc,
                                                    float* __restrict__ out) {
    __shared__ float sv[256];
    __shared__ int si[256];
    __shared__ float sxy[2];
    __shared__ float tile[64][65];
    const int tid = threadIdx.x;

    // argmax over 441 (first-occurrence tie-break)
    {
        float v = -1e30f; int vi = 0;
        for (int k = tid; k < SS * SS; k += 256) {
            float q = ncc[k];
            if (q > v) { v = q; vi = k; }
        }
        sv[tid] = v; si[tid] = vi;
        __syncthreads();
        for (int off = 128; off > 0; off >>= 1) {
            if (tid < off) {
                float v2 = sv[tid + off]; int i2 = si[tid + off];
                if (v2 > sv[tid] || (v2 == sv[tid] && i2 < si[tid])) { sv[tid] = v2; si[tid] = i2; }
            }
            __syncthreads();
        }
        if (tid == 0) {
            int idx = si[0];
            int sx = idx / SS;
            int sy = idx - sx * SS;
            auto at = [&](int r, int c) -> float {
                r = r < 0 ? 0 : (r > SS - 1 ? SS - 1 : r);
                c = c < 0 ? 0 : (c > SS - 1 ? SS - 1 : c);
                return logf(ncc[r * SS + c]);
            };
            float l4 = 4.0f * at(sx, sy);
            float lxm = at(sx - 1, sy), lxp = at(sx + 1, sy);
            float lym = at(sx, sy - 1), lyp = at(sx, sy + 1);
            float xsv = -((float)sx - (float)MS) - (lxm - lxp) / (2.0f * lxm - l4 + 2.0f * lxp);
            float ysv = -((float)sy - (float)MS) - (lym - lyp) / (2.0f * lym - l4 + 2.0f * lyp);
            sxy[0] = xsv; sxy[1] = ysv;
            if (blockIdx.x == 0 && blockIdx.y == 0) {
                out[(size_t)HH * WW] = xsv;
                out[(size_t)HH * WW + 1] = ysv;
            }
        }
        __syncthreads();
    }

    const float xs = sxy[0], ys = sxy[1];
    const int R0 = blockIdx.y * 64, C0 = blockIdx.x * 64;
    {
        const int cl = tid & 63, rg = tid >> 6;
        const int c = C0 + cl;
        const float cc = (float)c - ys;
        const float c0f = floorf(cc);
        const float wc = cc - c0f;
        const int c0 = (int)c0f;
        const bool vc0 = (c0 >= 0) & (c0 < WW);
        const bool vc1 = (c0 + 1 >= 0) & (c0 + 1 < WW);
        const int c0c = c0 < 0 ? 0 : (c0 > WW - 1 ? WW - 1 : c0);
        const int c1c = (c0 + 1) < 0 ? 0 : ((c0 + 1) > WW - 1 ? WW - 1 : c0 + 1);
        for (int k = 0; k < 16; ++k) {
            const int rl = rg * 16 + k;
            const int r = R0 + rl;
            const float rr = (float)r - xs;
            const float r0f = floorf(rr);
            const float wr = rr - r0f;
            const int r0 = (int)r0f;
            const bool vr0 = (r0 >= 0) & (r0 < HH);
            const bool vr1 = (r0 + 1 >= 0) & (r0 + 1 < HH);
            const int r0c = r0 < 0 ? 0 : (r0 > HH - 1 ? HH - 1 : r0);
            const int r1c = (r0 + 1) < 0 ? 0 : ((r0 + 1) > HH - 1 ? HH - 1 : r0 + 1);
            float s00 = img[(size_t)r0c * WW + c0c]; if (!(vr0 & vc0)) s00 = 0.f;
            float s01 = img[(size_t)r0c * WW + c1c]; if (!(vr0 & vc1)) s01 = 0.f;
            float s10 = img[(size_t)r1c * WW + c0c]; if (!(vr1 & vc0)) s10 = 0.f;
            float s11 = img[(size_t)r1c * WW + c1c]; if (!(vr1 & vc1)) s11 = 0.f;
            tile[rl][cl] = (1.f - wr) * (1.f - wc) * s00 + (1.f - wr) * wc * s01 +
                           wr * (1.f - wc) * s10 + wr * wc * s11;
        }
    }
    __syncthreads();
    {
        const int rl = tid & 63, cg = tid >> 6;
        for (int k = 0; k < 16; ++k) {
            const int cl = cg * 16 + k;
            out[(size_t)(C0 + cl) * HH + R0 + rl] = tile[rl][cl];
        }
    }
}

extern "C" void kernel_launch(void* const* d_in, const int* in_sizes, int n_in,
                              void* d_out, int out_size, void* d_ws, size_t ws_size,
                              hipStream_t stream) {
    const float* X = (const float*)d_in[0];
    const float* T = (const float*)d_in[1];
    float* out = (float*)d_out;

    char* w = (char*)d_ws;
    float* RS1T  = (float*)(w + 0);
    float* RS2T  = (float*)(w + 75600);
    float* Trow1 = (float*)(w + 151200);
    float* Trow2 = (float*)(w + 154720);
    float* Sfull = (float*)(w + 158240);
    float* part  = (float*)(w + 161840);
    float* ncc   = (float*)(w + 258880);

    row_stats_kernel<<<CD + TW, 256, 0, stream>>>(X, T, RS1T, RS2T, Trow1, Trow2, Sfull);
    corr_kernel<<<dim3(NBAND, SS), 256, 0, stream>>>(X, T, part);
    ncc_final_kernel<<<SS * SS, 256, 0, stream>>>(part, RS1T, RS2T, Trow1, Trow2, Sfull, ncc);
    shift_kernel<<<dim3(16, 16), 256, 0, stream>>>(X, ncc, out);
}